// Round 6
// baseline (612.262 us; speedup 1.0000x reference)
//
#include <hip/hip_runtime.h>
#include <hip/hip_bf16.h>
#include <math.h>

#define IN_CH 128
#define HID 64
#define OUT_CH 40

typedef const __hip_bfloat16* bf16p;
typedef __attribute__((ext_vector_type(8))) short v8s;
typedef __attribute__((ext_vector_type(4))) float v4f;

// ---- flag detection: flags[0]=1 if float tensors are f32, flags[1]=1 if indices are int64
__global__ void k_detect(const void* x, const void* ei, int* flags) {
    __shared__ int s_f32, s_hi;
    if (threadIdx.x == 0) { s_f32 = 0; s_hi = 0; }
    __syncthreads();
    const __hip_bfloat16* xb = (const __hip_bfloat16*)x;
    const int* ii = (const int*)ei;
    int lf = 0, lh = 0;
    for (int i = threadIdx.x; i < 4096; i += blockDim.x) {
        float f = __bfloat162float(xb[i]);
        if (!(fabsf(f) <= 1e4f)) lf = 1;       // huge/NaN -> buffer is really f32
        lh |= ii[2 * i + 1];                    // int64 high words are all zero
    }
    if (lf) atomicOr(&s_f32, 1);
    if (lh) atomicOr(&s_hi, 1);
    __syncthreads();
    if (threadIdx.x == 0) { flags[0] = s_f32 ? 1 : 0; flags[1] = (s_hi == 0) ? 1 : 0; }
}

// ---- weights to f32 table wf = [W1f 8192 | b1f 64 | W2f 2560 | b2f 40],
//      plus W1 packed into MFMA B-fragment order (bf16):
//      w1frag[((kb*4+cb)*64+lane)*8+j] = W1[kb*32+(lane>>4)*8+j][cb*16+(lane&15)]
__global__ void k_convw(const void* W1, const void* b1, const void* W2, const void* b2,
                        const int* flags, float* wf, __hip_bfloat16* w1frag) {
    int i = blockIdx.x * blockDim.x + threadIdx.x;
    if (i >= 19048) return;
    int isF32 = flags[0];
    if (i < 10856) {
        const void* src; int off;
        if (i < 8192)       { src = W1; off = i; }
        else if (i < 8256)  { src = b1; off = i - 8192; }
        else if (i < 10816) { src = W2; off = i - 8256; }
        else                { src = b2; off = i - 10816; }
        float v;
        if (isF32) v = ((const float*)src)[off];
        else       v = __bfloat162float(((bf16p)src)[off]);
        wf[i] = v;
    } else {
        int t = i - 10856;
        int j = t & 7, lane = (t >> 3) & 63, cb = (t >> 9) & 3, kb = t >> 11;
        int k = kb * 32 + ((lane >> 4) & 3) * 8 + j;
        int c = cb * 16 + (lane & 15);
        float v;
        if (isF32) v = ((const float*)W1)[k * HID + c];
        else       v = __bfloat162float(((bf16p)W1)[k * HID + c]);
        w1frag[t] = __float2bfloat16(v);
    }
}

// ---- in-degree histogram over col (int)
__global__ void k_deg(const int* ei, const int* flags, int* deg, int E) {
    int e = blockIdx.x * blockDim.x + threadIdx.x;
    if (e >= E) return;
    int c;
    if (flags[1]) c = ei[2 * (E + e)];
    else          c = ei[E + e];
    atomicAdd(&deg[c], 1);
}

__global__ void k_dinv(const int* deg, float* dinv, int N) {
    int i = blockIdx.x * blockDim.x + threadIdx.x;
    if (i >= N) return;
    dinv[i] = rsqrtf((float)deg[i] + 1.0f);   // +1 = self-loop
}

// ---- exclusive scan over deg -> rowstart (3 kernels)
__global__ void k_blocksum(const int* deg, int* bsum, int N) {
    __shared__ int s[256];
    int i = blockIdx.x * 256 + threadIdx.x;
    s[threadIdx.x] = (i < N) ? deg[i] : 0;
    __syncthreads();
    for (int off = 128; off > 0; off >>= 1) {
        if (threadIdx.x < off) s[threadIdx.x] += s[threadIdx.x + off];
        __syncthreads();
    }
    if (threadIdx.x == 0) bsum[blockIdx.x] = s[0];
}

__global__ void k_scanbsum(int* bsum, int NB) {
    __shared__ int s[1024];
    __shared__ int carry_s;
    if (threadIdx.x == 0) carry_s = 0;
    __syncthreads();
    for (int base = 0; base < NB; base += 1024) {
        int i = base + threadIdx.x;
        int v = (i < NB) ? bsum[i] : 0;
        s[threadIdx.x] = v;
        __syncthreads();
        for (int off = 1; off < 1024; off <<= 1) {
            int t = (threadIdx.x >= off) ? s[threadIdx.x - off] : 0;
            __syncthreads();
            s[threadIdx.x] += t;
            __syncthreads();
        }
        int total = s[1023];
        int excl = s[threadIdx.x] - v + carry_s;
        if (i < NB) bsum[i] = excl;
        __syncthreads();
        if (threadIdx.x == 0) carry_s += total;
        __syncthreads();
    }
}

__global__ void k_scanfinal(const int* deg, const int* boff, int* rowstart, int N) {
    __shared__ int s[256];
    int i = blockIdx.x * 256 + threadIdx.x;
    int v = (i < N) ? deg[i] : 0;
    s[threadIdx.x] = v;
    __syncthreads();
    for (int off = 1; off < 256; off <<= 1) {
        int t = (threadIdx.x >= off) ? s[threadIdx.x - off] : 0;
        __syncthreads();
        s[threadIdx.x] += t;
        __syncthreads();
    }
    if (i < N) rowstart[i] = boff[blockIdx.x] + s[threadIdx.x] - v;
    if (i == N - 1) rowstart[N] = boff[blockIdx.x] + s[threadIdx.x];
}

// ---- bucket-scatter edges into CSR, XCD-sliced: slice = blockIdx & 7 owns
//      destinations [slice*N/8,(slice+1)*N/8) so erow writes stay in one XCD's L2.
__global__ void k_scatter(const int* ei, const int* flags, const int* rowstart,
                          int* fill, int* erow, int E, int N) {
    int slice = blockIdx.x & 7;
    int nlo = (int)(((long)N * slice) >> 3);
    int nhi = (int)(((long)N * (slice + 1)) >> 3);
    int nblk = gridDim.x >> 3;
    int bid = blockIdx.x >> 3;
    int i64 = flags[1];
    for (int e = bid * 256 + threadIdx.x; e < E; e += nblk * 256) {
        int r, c;
        if (i64) { r = ei[2 * e]; c = ei[2 * (E + e)]; }
        else     { r = ei[e];     c = ei[E + e]; }
        if (c >= nlo && c < nhi) {
            int pos = rowstart[c] + atomicAdd(&fill[c], 1);
            erow[pos] = r;
        }
    }
}

// ---- GEMM1 via MFMA: h1b[n][c] = bf16(sum_k x[n][k]*W1[k][c]); one wave per 16-node tile.
//      A-frag: lane holds x[base+(lane&15)][kb*32+(lane>>4)*8 .. +8] (16B load).
//      B-frags (16) preloaded from w1frag into registers.
//      D: col(lane&15)=channel-within-block, row((lane>>4)*4+reg)=node-within-tile.
__global__ __launch_bounds__(256) void k_gemm1(const void* x, const float* wf,
                                               const __hip_bfloat16* w1frag,
                                               __hip_bfloat16* h1b, const int* flags, int N) {
    const int isF32 = flags[0];
    const int lane = threadIdx.x & 63;
    const int wid = blockIdx.x * 4 + (threadIdx.x >> 6);
    const int nwaves = gridDim.x * 4;
    if (!isF32) {
        const short* wfr = (const short*)w1frag;
        v8s bfr[16];
        #pragma unroll
        for (int q = 0; q < 16; ++q)
            bfr[q] = *(const v8s*)(wfr + (q * 64 + lane) * 8);
        const int m = lane & 15, quad = lane >> 4;
        const int ntiles = (N + 15) / 16;
        for (int tile = wid; tile < ntiles; tile += nwaves) {
            int nbase = tile * 16;
            int node = nbase + m; if (node >= N) node = N - 1;
            const short* xrow = (const short*)x + (size_t)node * IN_CH + quad * 8;
            v4f a0 = {0,0,0,0}, a1 = {0,0,0,0}, a2 = {0,0,0,0}, a3 = {0,0,0,0};
            #pragma unroll
            for (int kb = 0; kb < 4; ++kb) {
                v8s af = *(const v8s*)(xrow + kb * 32);
                a0 = __builtin_amdgcn_mfma_f32_16x16x32_bf16(af, bfr[kb*4+0], a0, 0, 0, 0);
                a1 = __builtin_amdgcn_mfma_f32_16x16x32_bf16(af, bfr[kb*4+1], a1, 0, 0, 0);
                a2 = __builtin_amdgcn_mfma_f32_16x16x32_bf16(af, bfr[kb*4+2], a2, 0, 0, 0);
                a3 = __builtin_amdgcn_mfma_f32_16x16x32_bf16(af, bfr[kb*4+3], a3, 0, 0, 0);
            }
            #pragma unroll
            for (int reg = 0; reg < 4; ++reg) {
                int n = nbase + quad * 4 + reg;
                if (n < N) {
                    __hip_bfloat16* hr = h1b + (size_t)n * HID + m;
                    hr[0]  = __float2bfloat16(a0[reg]);
                    hr[16] = __float2bfloat16(a1[reg]);
                    hr[32] = __float2bfloat16(a2[reg]);
                    hr[48] = __float2bfloat16(a3[reg]);
                }
            }
        }
    } else {
        // f32 fallback (VALU)
        const int c = lane;
        for (int n = wid; n < N; n += nwaves) {
            const float* xr = (const float*)x + (size_t)n * IN_CH;
            float acc = 0.f;
            #pragma unroll 8
            for (int k = 0; k < IN_CH; ++k) acc += xr[k] * wf[k * HID + c];
            h1b[(size_t)n * HID + c] = __float2bfloat16(acc);
        }
    }
}

// ---- Fused aggregation1 (+self-loop+bias+ReLU) AND GEMM2: one wave per node.
__global__ __launch_bounds__(256) void k_agg1gemm2(const int* rowstart, const int* erow,
        const __hip_bfloat16* h1b, const float* dinv, const float* b1f, const float* w2f,
        float* h2, int N) {
    __shared__ float w2[HID * OUT_CH];   // 2560 floats
    __shared__ float sg[256];            // per-wave g slices
    for (int i = threadIdx.x; i < HID * OUT_CH; i += 256) w2[i] = w2f[i];
    __syncthreads();

    int w = (blockIdx.x * 256 + threadIdx.x) >> 6;
    int c = threadIdx.x & 63;
    bool act = (w < N);
    float g = 0.f;
    if (act) {
        int s0 = __builtin_amdgcn_readfirstlane(rowstart[w]);
        int s1 = __builtin_amdgcn_readfirstlane(rowstart[w + 1]);
        float d = dinv[w];
        float acc = __bfloat162float(h1b[(size_t)w * HID + c]) * d * d + b1f[c];
        int i = s0;
        for (; i + 1 < s1; i += 2) {
            int r0 = erow[i];     int r1 = erow[i + 1];
            float n0 = dinv[r0] * d;
            float n1 = dinv[r1] * d;
            float v0 = __bfloat162float(h1b[(size_t)r0 * HID + c]);
            float v1 = __bfloat162float(h1b[(size_t)r1 * HID + c]);
            acc += v0 * n0 + v1 * n1;
        }
        if (i < s1) {
            int r = erow[i];
            acc += __bfloat162float(h1b[(size_t)r * HID + c]) * (dinv[r] * d);
        }
        g = fmaxf(acc, 0.f);
    }
    sg[threadIdx.x] = g;
    __syncthreads();
    if (act && c < OUT_CH) {
        const float* gs = sg + (threadIdx.x & 192);   // this wave's 64-slice
        float acc2 = 0.f;
        #pragma unroll
        for (int k = 0; k < HID; ++k) acc2 += gs[k] * w2[k * OUT_CH + c];
        h2[(size_t)w * OUT_CH + c] = acc2;
    }
}

// ---- Aggregation 2 (CSR): one wave per node, lanes 0..39 = channels; fused final -> d_out
__global__ __launch_bounds__(256) void k_agg2_csr(const int* rowstart, const int* erow,
        const float* h2, const float* dinv, const float* b2f, float* out, int N) {
    int w = (blockIdx.x * 256 + threadIdx.x) >> 6;
    int c = threadIdx.x & 63;
    if (w >= N) return;
    int s0 = __builtin_amdgcn_readfirstlane(rowstart[w]);
    int s1 = __builtin_amdgcn_readfirstlane(rowstart[w + 1]);
    float d = dinv[w];
    float acc = 0.f;
    if (c < OUT_CH) acc = h2[(size_t)w * OUT_CH + c] * d * d + b2f[c];
    int i = s0;
    for (; i + 1 < s1; i += 2) {
        int r0 = erow[i];     int r1 = erow[i + 1];
        float n0 = dinv[r0] * d;
        float n1 = dinv[r1] * d;
        if (c < OUT_CH) {
            float v0 = h2[(size_t)r0 * OUT_CH + c];
            float v1 = h2[(size_t)r1 * OUT_CH + c];
            acc += v0 * n0 + v1 * n1;
        }
    }
    if (i < s1 && c < OUT_CH) {
        int r = erow[i];
        acc += h2[(size_t)r * OUT_CH + c] * (dinv[r] * d);
    }
    if (c < OUT_CH) out[(size_t)w * OUT_CH + c] = acc;
}

extern "C" void kernel_launch(void* const* d_in, const int* in_sizes, int n_in,
                              void* d_out, int out_size, void* d_ws, size_t ws_size,
                              hipStream_t stream) {
    const void* x  = d_in[0];
    const void* ei = d_in[1];
    const void* W1 = d_in[2];
    const void* b1 = d_in[3];
    const void* W2 = d_in[4];
    const void* b2 = d_in[5];
    const int N = in_sizes[0] / IN_CH;   // 100000
    const int E = in_sizes[1] / 2;       // 1600000
    const int* eii = (const int*)ei;
    const int NB = (N + 255) / 256;

    // ---- workspace layout (4-byte units). Peak ≈ 37 MiB.
    float* ws = (float*)d_ws;
    size_t off = 16;
    int*   flags    = (int*)ws;
    int*   deg      = (int*)ws + off;            off += N;
    int*   fill     = (int*)ws + off;            off += N;   // contiguous with deg: one memset
    float* dinv     = ws + off;                  off += N;
    float* wf       = ws + off;                  off += 10880;
    __hip_bfloat16* w1frag = (__hip_bfloat16*)(ws + off);  off += 4096;  // 8192 bf16
    int*   bsum     = (int*)ws + off;            off += NB + 16;
    int*   rowstart = (int*)ws + off;            off += N + 1;
    off = (off + 255) & ~(size_t)255;
    int*   erow     = (int*)ws + off;            off += E;
    __hip_bfloat16* h1b = (__hip_bfloat16*)(ws + off);     off += (size_t)N * HID / 2;
    float* h2       = ws + off;                  off += (size_t)N * OUT_CH;

    hipMemsetAsync(deg, 0, (size_t)2 * N * sizeof(int), stream);  // deg + fill

    k_detect<<<1, 256, 0, stream>>>(x, ei, flags);
    k_convw<<<(19048 + 255) / 256, 256, 0, stream>>>(W1, b1, W2, b2, flags, wf, w1frag);
    k_deg<<<(E + 255) / 256, 256, 0, stream>>>(eii, flags, deg, E);
    k_dinv<<<(N + 255) / 256, 256, 0, stream>>>(deg, dinv, N);

    k_blocksum<<<NB, 256, 0, stream>>>(deg, bsum, N);
    k_scanbsum<<<1, 1024, 0, stream>>>(bsum, NB);
    k_scanfinal<<<NB, 256, 0, stream>>>(deg, bsum, rowstart, N);
    k_scatter<<<2048, 256, 0, stream>>>(eii, flags, rowstart, fill, erow, E, N);

    k_gemm1<<<1024, 256, 0, stream>>>(x, wf, w1frag, h1b, flags, N);

    int nodeBlocks = (N * 64 + 255) / 256;   // 25000
    k_agg1gemm2<<<nodeBlocks, 256, 0, stream>>>(rowstart, erow, h1b, dinv,
                                                wf + 8192, wf + 8256, h2, N);

    k_agg2_csr<<<nodeBlocks, 256, 0, stream>>>(rowstart, erow, h2, dinv,
                                               wf + 10816, (float*)d_out, N);
}